// Round 1
// baseline (482.117 us; speedup 1.0000x reference)
//
#include <hip/hip_runtime.h>
#include <hip/hip_bf16.h>

using bf16 = __bf16;
using bf16x8 = __attribute__((ext_vector_type(8))) __bf16;
using bf16x4 = __attribute__((ext_vector_type(4))) __bf16;
using f32x4  = __attribute__((ext_vector_type(4))) float;

typedef const void __attribute__((address_space(1)))* gas_p;
typedef void __attribute__((address_space(3)))* las_p;

#define GLD16(g, l) __builtin_amdgcn_global_load_lds((gas_p)(const void*)(g), (las_p)(void*)(l), 16, 0, 0)

__device__ __forceinline__ bf16x8 lds_ld8(const void* p) {
  union { uint4 u; bf16x8 v; } c;
  c.u = *(const uint4*)p;
  return c.v;
}

// ---------------- f32 -> bf16 elementwise convert ----------------
__global__ void k_convert(const float* __restrict__ in, bf16* __restrict__ out, int n4) {
  int i = blockIdx.x * blockDim.x + threadIdx.x;
  if (i >= n4) return;
  float4 f = ((const float4*)in)[i];
  bf16x4 o;
  o[0] = (bf16)f.x; o[1] = (bf16)f.y; o[2] = (bf16)f.z; o[3] = (bf16)f.w;
  ((bf16x4*)out)[i] = o;
}

// ---------------- transpose + convert weights: W[K=2048][N] -> Wt[N][2048] bf16 ----------------
__global__ void k_transp(const float* __restrict__ W, bf16* __restrict__ Wt, int N, int rowOff) {
  __shared__ float tile[64][65];
  const int n0 = blockIdx.x * 64, k0 = blockIdx.y * 64;
  const int t = threadIdx.x;
#pragma unroll
  for (int i = 0; i < 16; ++i) {
    int idx = t + i * 256; int r = idx >> 6, c = idx & 63;
    tile[r][c] = W[(size_t)(k0 + r) * N + n0 + c];
  }
  __syncthreads();
#pragma unroll
  for (int i = 0; i < 16; ++i) {
    int idx = t + i * 256; int r = idx >> 6, c = idx & 63;
    Wt[(size_t)(rowOff + n0 + r) * 2048 + k0 + c] = (bf16)tile[c][r];
  }
}

// ---------------- GEMM main loop: C[128x128] += A[128xK] * Bt[128xK]^T, K=2048, BK=32 ----------------
__device__ __forceinline__ void gemm_main(const bf16* __restrict__ A, const bf16* __restrict__ Bt,
                                          int brow, int bcol, int tid, f32x4 (&acc)[4][4],
                                          char* ldsA, char* ldsB) {
  const int lane = tid & 63;
  const int l15 = lane & 15, l4 = lane >> 4;
  const int wid = tid >> 6, wr = wid >> 1, wc = wid & 1;
  const int srow = tid >> 2;
  const int sseg = (tid & 3) ^ (srow & 3);   // pre-swizzled global source (m173 pattern)
  const bf16* ga = A  + (size_t)(brow + srow) * 2048 + sseg * 8;
  const bf16* gb = Bt + (size_t)(bcol + srow) * 2048 + sseg * 8;
  char* la = ldsA + tid * 16;
  char* lb = ldsB + tid * 16;
  const int roff = (l15 & 3) << 4;

  for (int k0 = 0; k0 < 2048; k0 += 32) {
    __syncthreads();
    GLD16(ga + k0, la);
    GLD16(ga + k0 + (size_t)64 * 2048, la + 4096);
    GLD16(gb + k0, lb);
    GLD16(gb + k0 + (size_t)64 * 2048, lb + 4096);
    __syncthreads();
    bf16x8 af[4], bfr[4];
#pragma unroll
    for (int m = 0; m < 4; ++m)
      af[m] = lds_ld8(ldsA + (wr * 64 + m * 16 + l15) * 64 + ((l4 << 4) ^ roff));
#pragma unroll
    for (int n = 0; n < 4; ++n)
      bfr[n] = lds_ld8(ldsB + (wc * 64 + n * 16 + l15) * 64 + ((l4 << 4) ^ roff));
#pragma unroll
    for (int m = 0; m < 4; ++m)
#pragma unroll
      for (int n = 0; n < 4; ++n)
        acc[m][n] = __builtin_amdgcn_mfma_f32_16x16x32_bf16(af[m], bfr[n], acc[m][n], 0, 0, 0);
  }
}

// ---------------- QKV GEMM + RoPE epilogue ----------------
__global__ __launch_bounds__(256) void k_gemm_qkv(const bf16* __restrict__ A, const bf16* __restrict__ Bt,
    const float* __restrict__ cosT, const float* __restrict__ sinT,
    bf16* __restrict__ Qb, bf16* __restrict__ Kb, bf16* __restrict__ Vb) {
  __shared__ __align__(16) char ldsA[8192];
  __shared__ __align__(16) char ldsB[8192];
  const int tid = threadIdx.x;
  const int brow = blockIdx.x * 128, bcol = blockIdx.y * 128;
  f32x4 zero = {0.f, 0.f, 0.f, 0.f};
  f32x4 acc[4][4];
#pragma unroll
  for (int m = 0; m < 4; ++m)
#pragma unroll
    for (int n = 0; n < 4; ++n) acc[m][n] = zero;

  gemm_main(A, Bt, brow, bcol, tid, acc, ldsA, ldsB);

  const int lane = tid & 63, l15 = lane & 15, l4 = lane >> 4;
  const int wid = tid >> 6, wr = wid >> 1, wc = wid & 1;
  const int base64 = bcol + wc * 64;       // wave-uniform; one head per wave block
  const int rbase  = brow + wr * 64;

  if (base64 < 2048) {                      // Q segment (RoPE + 1/sqrt(64) scale)
    const int h = base64 >> 6;
#pragma unroll
    for (int m = 0; m < 4; ++m)
#pragma unroll
      for (int r = 0; r < 4; ++r) {
        const int row = rbase + m * 16 + l4 * 4 + r;
        const int b = row >> 11, s = row & 2047;
        float o[4];
#pragma unroll
        for (int n = 0; n < 4; ++n) {
          const int d = n * 16 + l15;
          const float cv = cosT[s * 64 + d], sv = sinT[s * 64 + d];
          const float t = acc[m][n][r], p = acc[m][n ^ 2][r];
          o[n] = (t * cv + ((n < 2) ? -p : p) * sv) * 0.125f;
        }
        bf16* dst = Qb + ((size_t)((b * 32 + h) * 2048 + s)) * 64;
#pragma unroll
        for (int n = 0; n < 4; ++n) dst[n * 16 + l15] = (bf16)o[n];
      }
  } else if (base64 < 2560) {               // K segment (RoPE)
    const int h = (base64 - 2048) >> 6;
#pragma unroll
    for (int m = 0; m < 4; ++m)
#pragma unroll
      for (int r = 0; r < 4; ++r) {
        const int row = rbase + m * 16 + l4 * 4 + r;
        const int b = row >> 11, s = row & 2047;
        float o[4];
#pragma unroll
        for (int n = 0; n < 4; ++n) {
          const int d = n * 16 + l15;
          const float cv = cosT[s * 64 + d], sv = sinT[s * 64 + d];
          const float t = acc[m][n][r], p = acc[m][n ^ 2][r];
          o[n] = t * cv + ((n < 2) ? -p : p) * sv;
        }
        bf16* dst = Kb + ((size_t)((b * 8 + h) * 2048 + s)) * 64;
#pragma unroll
        for (int n = 0; n < 4; ++n) dst[n * 16 + l15] = (bf16)o[n];
      }
  } else {                                  // V segment (plain)
    const int h = (base64 - 2560) >> 6;
#pragma unroll
    for (int m = 0; m < 4; ++m)
#pragma unroll
      for (int r = 0; r < 4; ++r) {
        const int row = rbase + m * 16 + l4 * 4 + r;
        const int b = row >> 11, s = row & 2047;
        bf16* dst = Vb + ((size_t)((b * 8 + h) * 2048 + s)) * 64;
#pragma unroll
        for (int n = 0; n < 4; ++n) dst[n * 16 + l15] = (bf16)acc[m][n][r];
      }
  }
}

// ---------------- Flash attention (causal, GQA) ----------------
__global__ __launch_bounds__(256) void k_attn(const bf16* __restrict__ Qb, const bf16* __restrict__ Kb,
                                              const bf16* __restrict__ Vb, bf16* __restrict__ ctx) {
  __shared__ __align__(16) char kl[8192];      // K tile [64 kv][64 d], XOR-swizzled rows
  __shared__ __align__(16) char vl[8192];      // V^T tile [64 d][64 kv], XOR-swizzled rows
  __shared__ __align__(16) char pl[4][2048];   // per-wave P [16 q][64 kv], XOR-swizzled
  const int tid = threadIdx.x, lane = tid & 63, w = tid >> 6;
  const int l15 = lane & 15, l4 = lane >> 4;
  const int qb = (int)gridDim.x - 1 - (int)blockIdx.x;  // heavy blocks first
  const int bh = blockIdx.y, b = bh >> 5, h = bh & 31, hk = h >> 2;
  const int q0 = qb * 64 + w * 16;
  const int swz = (l15 & 7) << 4;

  const bf16* qg = Qb + ((size_t)((b * 32 + h) * 2048) + q0 + l15) * 64 + l4 * 8;
  bf16x8 aq[2];
  aq[0] = *(const bf16x8*)(qg);
  aq[1] = *(const bf16x8*)(qg + 32);

  const bf16* kg = Kb + ((size_t)((b * 8 + hk) * 2048)) * 64;
  const bf16* vg = Vb + ((size_t)((b * 8 + hk) * 2048)) * 64;

  f32x4 zero = {0.f, 0.f, 0.f, 0.f};
  f32x4 o[4] = {zero, zero, zero, zero};
  float mrow[4] = {-3.0e38f, -3.0e38f, -3.0e38f, -3.0e38f};
  float lrow[4] = {0.f, 0.f, 0.f, 0.f};

  for (int kt = 0; kt <= qb; ++kt) {
    const int kv0 = kt * 64;
    __syncthreads();
    // stage K tile (vectorized) and V^T tile (scalar transpose writes)
#pragma unroll
    for (int it = 0; it < 2; ++it) {
      const int row = it * 32 + (tid >> 3), seg = tid & 7;
      uint4 dK = *(const uint4*)(kg + (size_t)(kv0 + row) * 64 + seg * 8);
      *(uint4*)(kl + row * 128 + ((seg * 16) ^ ((row & 7) << 4))) = dK;
      bf16x8 vv = *(const bf16x8*)(vg + (size_t)(kv0 + row) * 64 + seg * 8);
#pragma unroll
      for (int j = 0; j < 8; ++j) {
        const int d = seg * 8 + j;
        *(bf16*)(vl + d * 128 + ((row * 2) ^ ((d & 7) << 4))) = vv[j];
      }
    }
    __syncthreads();

    // scores: 16(q) x 64(kv) per wave
    f32x4 sc[4] = {zero, zero, zero, zero};
#pragma unroll
    for (int n = 0; n < 4; ++n) {
      const int row = n * 16 + l15;
#pragma unroll
      for (int kk = 0; kk < 2; ++kk) {
        bf16x8 bk = lds_ld8(kl + row * 128 + ((kk * 64 + l4 * 16) ^ swz));
        sc[n] = __builtin_amdgcn_mfma_f32_16x16x32_bf16(aq[kk], bk, sc[n], 0, 0, 0);
      }
    }
    if (kt == qb) {   // diagonal tile: per-element causal mask
#pragma unroll
      for (int n = 0; n < 4; ++n) {
        const int kv = kv0 + n * 16 + l15;
#pragma unroll
        for (int r = 0; r < 4; ++r) {
          const int q = q0 + l4 * 4 + r;
          if (kv > q) sc[n][r] = -3.0e30f;
        }
      }
    }
    // online softmax (row groups share l4; reduce across low 4 lane bits)
    float pr[4][4];
#pragma unroll
    for (int r = 0; r < 4; ++r) {
      float mx = fmaxf(fmaxf(sc[0][r], sc[1][r]), fmaxf(sc[2][r], sc[3][r]));
      mx = fmaxf(mx, __shfl_xor(mx, 1));
      mx = fmaxf(mx, __shfl_xor(mx, 2));
      mx = fmaxf(mx, __shfl_xor(mx, 4));
      mx = fmaxf(mx, __shfl_xor(mx, 8));
      const float mn = fmaxf(mrow[r], mx);
      const float corr = __expf(mrow[r] - mn);
      mrow[r] = mn;
      float rs = 0.f;
#pragma unroll
      for (int n = 0; n < 4; ++n) { float p = __expf(sc[n][r] - mn); pr[n][r] = p; rs += p; }
      rs += __shfl_xor(rs, 1); rs += __shfl_xor(rs, 2);
      rs += __shfl_xor(rs, 4); rs += __shfl_xor(rs, 8);
      lrow[r] = lrow[r] * corr + rs;
#pragma unroll
      for (int n = 0; n < 4; ++n) o[n][r] *= corr;
    }
    // P -> LDS (per-wave private), re-read as MFMA A-fragments
#pragma unroll
    for (int n = 0; n < 4; ++n) {
      const int kv = n * 16 + l15;
#pragma unroll
      for (int r = 0; r < 4; ++r) {
        const int q = l4 * 4 + r;
        *(bf16*)(pl[w] + q * 128 + ((kv * 2) ^ ((q & 7) << 4))) = (bf16)pr[n][r];
      }
    }
    // PV
#pragma unroll
    for (int kk = 0; kk < 2; ++kk) {
      bf16x8 pa = lds_ld8(pl[w] + l15 * 128 + ((kk * 64 + l4 * 16) ^ swz));
#pragma unroll
      for (int n = 0; n < 4; ++n) {
        const int d = n * 16 + l15;
        bf16x8 bv = lds_ld8(vl + d * 128 + ((kk * 64 + l4 * 16) ^ swz));
        o[n] = __builtin_amdgcn_mfma_f32_16x16x32_bf16(pa, bv, o[n], 0, 0, 0);
      }
    }
  }
  // normalize + store ctx[b][s][h*64+d]
#pragma unroll
  for (int r = 0; r < 4; ++r) {
    const float inv = 1.0f / lrow[r];
    const int q = q0 + l4 * 4 + r;
    bf16* dst = ctx + ((size_t)(b * 2048 + q)) * 2048 + h * 64;
#pragma unroll
    for (int n = 0; n < 4; ++n) dst[n * 16 + l15] = (bf16)(o[n][r] * inv);
  }
}

// ---------------- Output GEMM: ctx @ Wo -> f32 ----------------
__global__ __launch_bounds__(256) void k_gemm_out(const bf16* __restrict__ A, const bf16* __restrict__ Bt,
                                                  float* __restrict__ out) {
  __shared__ __align__(16) char ldsA[8192];
  __shared__ __align__(16) char ldsB[8192];
  const int tid = threadIdx.x;
  const int brow = blockIdx.x * 128, bcol = blockIdx.y * 128;
  f32x4 zero = {0.f, 0.f, 0.f, 0.f};
  f32x4 acc[4][4];
#pragma unroll
  for (int m = 0; m < 4; ++m)
#pragma unroll
    for (int n = 0; n < 4; ++n) acc[m][n] = zero;

  gemm_main(A, Bt, brow, bcol, tid, acc, ldsA, ldsB);

  const int lane = tid & 63, l15 = lane & 15, l4 = lane >> 4;
  const int wid = tid >> 6, wr = wid >> 1, wc = wid & 1;
#pragma unroll
  for (int m = 0; m < 4; ++m)
#pragma unroll
    for (int r = 0; r < 4; ++r) {
      const int row = brow + wr * 64 + m * 16 + l4 * 4 + r;
      float* dst = out + (size_t)row * 2048 + bcol + wc * 64;
#pragma unroll
      for (int n = 0; n < 4; ++n) dst[n * 16 + l15] = acc[m][n][r];
    }
}

extern "C" void kernel_launch(void* const* d_in, const int* in_sizes, int n_in,
                              void* d_out, int out_size, void* d_ws, size_t ws_size,
                              hipStream_t stream) {
  (void)in_sizes; (void)n_in; (void)out_size;
  if (ws_size < (size_t)79691776) return;   // need ~76 MB scratch
  const float* x    = (const float*)d_in[0];
  // d_in[1] = mask (causal, hardcoded)
  const float* cosT = (const float*)d_in[2];
  const float* sinT = (const float*)d_in[3];
  const float* Wq   = (const float*)d_in[4];
  const float* Wk   = (const float*)d_in[5];
  const float* Wv   = (const float*)d_in[6];
  const float* Wo   = (const float*)d_in[7];
  char* ws = (char*)d_ws;
  bf16* xb   = (bf16*)(ws + 0);            // [4096][2048]
  bf16* wqkv = (bf16*)(ws + 16777216);     // [3072][2048]  (Wq^T | Wk^T | Wv^T)
  bf16* wo_t = (bf16*)(ws + 29360128);     // [2048][2048]
  bf16* Qb   = (bf16*)(ws + 37748736);     // [2][32][2048][64]
  bf16* Kb   = (bf16*)(ws + 54525952);     // [2][8][2048][64]
  bf16* Vb   = (bf16*)(ws + 58720256);     // [2][8][2048][64]
  bf16* ctxb = (bf16*)(ws + 62914560);     // [4096][2048]
  float* out = (float*)d_out;

  k_convert<<<8192, 256, 0, stream>>>(x, xb, 2097152);
  k_transp<<<dim3(32, 32), 256, 0, stream>>>(Wq, wqkv, 2048, 0);
  k_transp<<<dim3(8, 32),  256, 0, stream>>>(Wk, wqkv, 512, 2048);
  k_transp<<<dim3(8, 32),  256, 0, stream>>>(Wv, wqkv, 512, 2560);
  k_transp<<<dim3(32, 32), 256, 0, stream>>>(Wo, wo_t, 2048, 0);
  k_gemm_qkv<<<dim3(32, 24), 256, 0, stream>>>(xb, wqkv, cosT, sinT, Qb, Kb, Vb);
  k_attn<<<dim3(32, 64), 256, 0, stream>>>(Qb, Kb, Vb, ctxb);
  k_gemm_out<<<dim3(32, 16), 256, 0, stream>>>(ctxb, wo_t, out);
}

// Round 2
// 464.444 us; speedup vs baseline: 1.0381x; 1.0381x over previous
//
#include <hip/hip_runtime.h>
#include <hip/hip_bf16.h>

using bf16 = __bf16;
using bf16x8 = __attribute__((ext_vector_type(8))) __bf16;
using bf16x4 = __attribute__((ext_vector_type(4))) __bf16;
using f32x4  = __attribute__((ext_vector_type(4))) float;

typedef const void __attribute__((address_space(1)))* gas_p;
typedef void __attribute__((address_space(3)))* las_p;

#define GLD16(g, l) __builtin_amdgcn_global_load_lds((gas_p)(const void*)(g), (las_p)(void*)(l), 16, 0, 0)

__device__ __forceinline__ bf16x8 lds_ld8(const void* p) {
  union { uint4 u; bf16x8 v; } c;
  c.u = *(const uint4*)p;
  return c.v;
}
__device__ __forceinline__ bf16x8 g_ld8(const bf16* p) {
  union { uint4 u; bf16x8 v; } c;
  c.u = *(const uint4*)p;
  return c.v;
}

// ---------------- f32 -> bf16 elementwise convert ----------------
__global__ void k_convert(const float* __restrict__ in, bf16* __restrict__ out, int n4) {
  int i = blockIdx.x * blockDim.x + threadIdx.x;
  if (i >= n4) return;
  float4 f = ((const float4*)in)[i];
  bf16x4 o;
  o[0] = (bf16)f.x; o[1] = (bf16)f.y; o[2] = (bf16)f.z; o[3] = (bf16)f.w;
  ((bf16x4*)out)[i] = o;
}

// ---------------- transpose + convert weights: W[K=2048][N] -> Wt[N][2048] bf16 ----------------
__global__ void k_transp(const float* __restrict__ W, bf16* __restrict__ Wt, int N, int rowOff) {
  __shared__ float tile[64][65];
  const int n0 = blockIdx.x * 64, k0 = blockIdx.y * 64;
  const int t = threadIdx.x;
#pragma unroll
  for (int i = 0; i < 16; ++i) {
    int idx = t + i * 256; int r = idx >> 6, c = idx & 63;
    tile[r][c] = W[(size_t)(k0 + r) * N + n0 + c];
  }
  __syncthreads();
#pragma unroll
  for (int i = 0; i < 16; ++i) {
    int idx = t + i * 256; int r = idx >> 6, c = idx & 63;
    Wt[(size_t)(rowOff + n0 + r) * 2048 + k0 + c] = (bf16)tile[c][r];
  }
}

// ---------------- GEMM main loop: C[128x128] += A[128xK] * Bt[128xK]^T, K=2048, BK=32 ----------------
__device__ __forceinline__ void gemm_main(const bf16* __restrict__ A, const bf16* __restrict__ Bt,
                                          int brow, int bcol, int tid, f32x4 (&acc)[4][4],
                                          char* ldsA, char* ldsB) {
  const int lane = tid & 63;
  const int l15 = lane & 15, l4 = lane >> 4;
  const int wid = tid >> 6, wr = wid >> 1, wc = wid & 1;
  const int srow = tid >> 2;
  const int sseg = (tid & 3) ^ (srow & 3);   // pre-swizzled global source (m173 pattern)
  const bf16* ga = A  + (size_t)(brow + srow) * 2048 + sseg * 8;
  const bf16* gb = Bt + (size_t)(bcol + srow) * 2048 + sseg * 8;
  char* la = ldsA + tid * 16;
  char* lb = ldsB + tid * 16;
  const int roff = (l15 & 3) << 4;

  for (int k0 = 0; k0 < 2048; k0 += 32) {
    __syncthreads();
    GLD16(ga + k0, la);
    GLD16(ga + k0 + (size_t)64 * 2048, la + 4096);
    GLD16(gb + k0, lb);
    GLD16(gb + k0 + (size_t)64 * 2048, lb + 4096);
    __syncthreads();
    bf16x8 af[4], bfr[4];
#pragma unroll
    for (int m = 0; m < 4; ++m)
      af[m] = lds_ld8(ldsA + (wr * 64 + m * 16 + l15) * 64 + ((l4 << 4) ^ roff));
#pragma unroll
    for (int n = 0; n < 4; ++n)
      bfr[n] = lds_ld8(ldsB + (wc * 64 + n * 16 + l15) * 64 + ((l4 << 4) ^ roff));
#pragma unroll
    for (int m = 0; m < 4; ++m)
#pragma unroll
      for (int n = 0; n < 4; ++n)
        acc[m][n] = __builtin_amdgcn_mfma_f32_16x16x32_bf16(af[m], bfr[n], acc[m][n], 0, 0, 0);
  }
}

// ---------------- QKV GEMM + RoPE epilogue (V written transposed) ----------------
__global__ __launch_bounds__(256) void k_gemm_qkv(const bf16* __restrict__ A, const bf16* __restrict__ Bt,
    const float* __restrict__ cosT, const float* __restrict__ sinT,
    bf16* __restrict__ Qb, bf16* __restrict__ Kb, bf16* __restrict__ Vt) {
  __shared__ __align__(16) char ldsA[8192];
  __shared__ __align__(16) char ldsB[8192];
  const int tid = threadIdx.x;
  const int brow = blockIdx.x * 128, bcol = blockIdx.y * 128;
  f32x4 zero = {0.f, 0.f, 0.f, 0.f};
  f32x4 acc[4][4];
#pragma unroll
  for (int m = 0; m < 4; ++m)
#pragma unroll
    for (int n = 0; n < 4; ++n) acc[m][n] = zero;

  gemm_main(A, Bt, brow, bcol, tid, acc, ldsA, ldsB);

  const int lane = tid & 63, l15 = lane & 15, l4 = lane >> 4;
  const int wid = tid >> 6, wr = wid >> 1, wc = wid & 1;
  const int base64 = bcol + wc * 64;       // wave-uniform; one head per wave block
  const int rbase  = brow + wr * 64;

  if (base64 < 2048) {                      // Q segment (RoPE + 1/sqrt(64) scale)
    const int h = base64 >> 6;
#pragma unroll
    for (int m = 0; m < 4; ++m)
#pragma unroll
      for (int r = 0; r < 4; ++r) {
        const int row = rbase + m * 16 + l4 * 4 + r;
        const int b = row >> 11, s = row & 2047;
        float o[4];
#pragma unroll
        for (int n = 0; n < 4; ++n) {
          const int d = n * 16 + l15;
          const float cv = cosT[s * 64 + d], sv = sinT[s * 64 + d];
          const float t = acc[m][n][r], p = acc[m][n ^ 2][r];
          o[n] = (t * cv + ((n < 2) ? -p : p) * sv) * 0.125f;
        }
        bf16* dst = Qb + ((size_t)((b * 32 + h) * 2048 + s)) * 64;
#pragma unroll
        for (int n = 0; n < 4; ++n) dst[n * 16 + l15] = (bf16)o[n];
      }
  } else if (base64 < 2560) {               // K segment (RoPE)
    const int h = (base64 - 2048) >> 6;
#pragma unroll
    for (int m = 0; m < 4; ++m)
#pragma unroll
      for (int r = 0; r < 4; ++r) {
        const int row = rbase + m * 16 + l4 * 4 + r;
        const int b = row >> 11, s = row & 2047;
        float o[4];
#pragma unroll
        for (int n = 0; n < 4; ++n) {
          const int d = n * 16 + l15;
          const float cv = cosT[s * 64 + d], sv = sinT[s * 64 + d];
          const float t = acc[m][n][r], p = acc[m][n ^ 2][r];
          o[n] = t * cv + ((n < 2) ? -p : p) * sv;
        }
        bf16* dst = Kb + ((size_t)((b * 8 + h) * 2048 + s)) * 64;
#pragma unroll
        for (int n = 0; n < 4; ++n) dst[n * 16 + l15] = (bf16)o[n];
      }
  } else {                                  // V segment -> transposed Vt[b][hk][d][s]
    const int h = (base64 - 2560) >> 6;
#pragma unroll
    for (int m = 0; m < 4; ++m)
#pragma unroll
      for (int r = 0; r < 4; ++r) {
        const int row = rbase + m * 16 + l4 * 4 + r;
        const int b = row >> 11, s = row & 2047;
#pragma unroll
        for (int n = 0; n < 4; ++n) {
          const int d = n * 16 + l15;
          Vt[((size_t)((b * 8 + h) * 64 + d)) * 2048 + s] = (bf16)acc[m][n][r];
        }
      }
  }
}

// ---------------- Flash attention (causal, GQA) ----------------
// One wave owns 32 q-rows; K and Vt MFMA fragments read directly from global
// (L2/L1-resident: 512 KB per (b,hk)); no barriers anywhere in the main loop.
__global__ __launch_bounds__(256) void k_attn(const bf16* __restrict__ Qb, const bf16* __restrict__ Kb,
                                              const bf16* __restrict__ Vt, bf16* __restrict__ ctx) {
  __shared__ __align__(16) char pl[4][2][2048];   // per-wave per-mi P [16 q][64 kv], XOR-swizzled
  const int tid = threadIdx.x, lane = tid & 63, w = tid >> 6;
  const int l15 = lane & 15, l4 = lane >> 4;
  const int wu = 63 - ((int)blockIdx.x * 4 + w);  // heavy waves first
  const int q0 = wu * 32;
  const int bh = blockIdx.y, b = bh >> 5, h = bh & 31, hk = h >> 2;
  const int swz = (l15 & 7) << 4;

  const bf16* qg = Qb + ((size_t)((b * 32 + h) * 2048) + q0) * 64;
  const bf16* kg = Kb + ((size_t)((b * 8 + hk) * 2048)) * 64;
  const bf16* vg = Vt + ((size_t)((b * 8 + hk) * 64)) * 2048;

  bf16x8 aq[2][2];
#pragma unroll
  for (int mi = 0; mi < 2; ++mi)
#pragma unroll
    for (int kk = 0; kk < 2; ++kk)
      aq[mi][kk] = g_ld8(qg + (mi * 16 + l15) * 64 + kk * 32 + l4 * 8);

  f32x4 zero = {0.f, 0.f, 0.f, 0.f};
  f32x4 o[2][4];
#pragma unroll
  for (int mi = 0; mi < 2; ++mi)
#pragma unroll
    for (int n = 0; n < 4; ++n) o[mi][n] = zero;
  float mrow[2][4], lrow[2][4];
#pragma unroll
  for (int mi = 0; mi < 2; ++mi)
#pragma unroll
    for (int r = 0; r < 4; ++r) { mrow[mi][r] = -3.0e38f; lrow[mi][r] = 0.f; }

  const int nfull = q0 >> 6;   // tiles 0..nfull-1 unmasked, tile nfull masked
  for (int kt = 0; kt <= nfull; ++kt) {
    const int kv0 = kt * 64;
    const bool masked = (kt == nfull);

    // ---- scores for both 16-row sub-blocks, K fragments straight from global ----
    f32x4 sc[2][4];
#pragma unroll
    for (int n = 0; n < 4; ++n) {
      const bf16* kr = kg + (size_t)(kv0 + n * 16 + l15) * 64 + l4 * 8;
      bf16x8 bk0 = g_ld8(kr);
      bf16x8 bk1 = g_ld8(kr + 32);
      sc[0][n] = __builtin_amdgcn_mfma_f32_16x16x32_bf16(aq[0][0], bk0, zero, 0, 0, 0);
      sc[0][n] = __builtin_amdgcn_mfma_f32_16x16x32_bf16(aq[0][1], bk1, sc[0][n], 0, 0, 0);
      sc[1][n] = __builtin_amdgcn_mfma_f32_16x16x32_bf16(aq[1][0], bk0, zero, 0, 0, 0);
      sc[1][n] = __builtin_amdgcn_mfma_f32_16x16x32_bf16(aq[1][1], bk1, sc[1][n], 0, 0, 0);
    }

#pragma unroll
    for (int mi = 0; mi < 2; ++mi) {
      if (masked) {
#pragma unroll
        for (int n = 0; n < 4; ++n) {
          const int kv = kv0 + n * 16 + l15;
#pragma unroll
          for (int r = 0; r < 4; ++r) {
            const int q = q0 + mi * 16 + l4 * 4 + r;
            if (kv > q) sc[mi][n][r] = -3.0e30f;
          }
        }
      }
      // online softmax: rows live across l15 (16 lanes); reduce over low 4 lane bits
#pragma unroll
      for (int r = 0; r < 4; ++r) {
        float mx = fmaxf(fmaxf(sc[mi][0][r], sc[mi][1][r]), fmaxf(sc[mi][2][r], sc[mi][3][r]));
        mx = fmaxf(mx, __shfl_xor(mx, 1));
        mx = fmaxf(mx, __shfl_xor(mx, 2));
        mx = fmaxf(mx, __shfl_xor(mx, 4));
        mx = fmaxf(mx, __shfl_xor(mx, 8));
        const float mn = fmaxf(mrow[mi][r], mx);
        const float corr = __expf(mrow[mi][r] - mn);
        mrow[mi][r] = mn;
        float pv0 = __expf(sc[mi][0][r] - mn), pv1 = __expf(sc[mi][1][r] - mn);
        float pv2 = __expf(sc[mi][2][r] - mn), pv3 = __expf(sc[mi][3][r] - mn);
        float rs = (pv0 + pv1) + (pv2 + pv3);
        rs += __shfl_xor(rs, 1); rs += __shfl_xor(rs, 2);
        rs += __shfl_xor(rs, 4); rs += __shfl_xor(rs, 8);
        lrow[mi][r] = lrow[mi][r] * corr + rs;
#pragma unroll
        for (int n = 0; n < 4; ++n) o[mi][n][r] *= corr;
        // P -> per-wave LDS (transpose to A-fragment layout)
        const int q = mi ? 0 : 0;  (void)q;
        const int qr = l4 * 4 + r;
        char* base = pl[w][mi];
        *(bf16*)(base + qr * 128 + (((0 * 16 + l15) * 2) ^ ((qr & 7) << 4))) = (bf16)pv0;
        *(bf16*)(base + qr * 128 + (((1 * 16 + l15) * 2) ^ ((qr & 7) << 4))) = (bf16)pv1;
        *(bf16*)(base + qr * 128 + (((2 * 16 + l15) * 2) ^ ((qr & 7) << 4))) = (bf16)pv2;
        *(bf16*)(base + qr * 128 + (((3 * 16 + l15) * 2) ^ ((qr & 7) << 4))) = (bf16)pv3;
      }
    }

    // ---- PV: P from per-wave LDS, V fragments straight from global (Vt rows) ----
#pragma unroll
    for (int kk = 0; kk < 2; ++kk) {
      bf16x8 pa0 = lds_ld8(pl[w][0] + l15 * 128 + ((kk * 64 + l4 * 16) ^ swz));
      bf16x8 pa1 = lds_ld8(pl[w][1] + l15 * 128 + ((kk * 64 + l4 * 16) ^ swz));
#pragma unroll
      for (int n = 0; n < 4; ++n) {
        bf16x8 bv = g_ld8(vg + (size_t)(n * 16 + l15) * 2048 + kv0 + kk * 32 + l4 * 8);
        o[0][n] = __builtin_amdgcn_mfma_f32_16x16x32_bf16(pa0, bv, o[0][n], 0, 0, 0);
        o[1][n] = __builtin_amdgcn_mfma_f32_16x16x32_bf16(pa1, bv, o[1][n], 0, 0, 0);
      }
    }
  }

  // normalize + store ctx[b][s][h*64+d]
#pragma unroll
  for (int mi = 0; mi < 2; ++mi)
#pragma unroll
    for (int r = 0; r < 4; ++r) {
      const float inv = 1.0f / lrow[mi][r];
      const int q = q0 + mi * 16 + l4 * 4 + r;
      bf16* dst = ctx + ((size_t)(b * 2048 + q)) * 2048 + h * 64;
#pragma unroll
      for (int n = 0; n < 4; ++n) dst[n * 16 + l15] = (bf16)(o[mi][n][r] * inv);
    }
}

// ---------------- Output GEMM: ctx @ Wo -> f32 ----------------
__global__ __launch_bounds__(256) void k_gemm_out(const bf16* __restrict__ A, const bf16* __restrict__ Bt,
                                                  float* __restrict__ out) {
  __shared__ __align__(16) char ldsA[8192];
  __shared__ __align__(16) char ldsB[8192];
  const int tid = threadIdx.x;
  const int brow = blockIdx.x * 128, bcol = blockIdx.y * 128;
  f32x4 zero = {0.f, 0.f, 0.f, 0.f};
  f32x4 acc[4][4];
#pragma unroll
  for (int m = 0; m < 4; ++m)
#pragma unroll
    for (int n = 0; n < 4; ++n) acc[m][n] = zero;

  gemm_main(A, Bt, brow, bcol, tid, acc, ldsA, ldsB);

  const int lane = tid & 63, l15 = lane & 15, l4 = lane >> 4;
  const int wid = tid >> 6, wr = wid >> 1, wc = wid & 1;
#pragma unroll
  for (int m = 0; m < 4; ++m)
#pragma unroll
    for (int r = 0; r < 4; ++r) {
      const int row = brow + wr * 64 + m * 16 + l4 * 4 + r;
      float* dst = out + (size_t)row * 2048 + bcol + wc * 64;
#pragma unroll
      for (int n = 0; n < 4; ++n) dst[n * 16 + l15] = acc[m][n][r];
    }
}

extern "C" void kernel_launch(void* const* d_in, const int* in_sizes, int n_in,
                              void* d_out, int out_size, void* d_ws, size_t ws_size,
                              hipStream_t stream) {
  (void)in_sizes; (void)n_in; (void)out_size;
  if (ws_size < (size_t)79691776) return;   // need ~76 MB scratch
  const float* x    = (const float*)d_in[0];
  // d_in[1] = mask (causal, hardcoded)
  const float* cosT = (const float*)d_in[2];
  const float* sinT = (const float*)d_in[3];
  const float* Wq   = (const float*)d_in[4];
  const float* Wk   = (const float*)d_in[5];
  const float* Wv   = (const float*)d_in[6];
  const float* Wo   = (const float*)d_in[7];
  char* ws = (char*)d_ws;
  bf16* xb   = (bf16*)(ws + 0);            // [4096][2048]
  bf16* wqkv = (bf16*)(ws + 16777216);     // [3072][2048]  (Wq^T | Wk^T | Wv^T)
  bf16* wo_t = (bf16*)(ws + 29360128);     // [2048][2048]
  bf16* Qb   = (bf16*)(ws + 37748736);     // [2][32][2048][64]
  bf16* Kb   = (bf16*)(ws + 54525952);     // [2][8][2048][64]
  bf16* Vt   = (bf16*)(ws + 58720256);     // [2][8][64][2048]  (transposed V)
  bf16* ctxb = (bf16*)(ws + 62914560);     // [4096][2048]
  float* out = (float*)d_out;

  k_convert<<<8192, 256, 0, stream>>>(x, xb, 2097152);
  k_transp<<<dim3(32, 32), 256, 0, stream>>>(Wq, wqkv, 2048, 0);
  k_transp<<<dim3(8, 32),  256, 0, stream>>>(Wk, wqkv, 512, 2048);
  k_transp<<<dim3(8, 32),  256, 0, stream>>>(Wv, wqkv, 512, 2560);
  k_transp<<<dim3(32, 32), 256, 0, stream>>>(Wo, wo_t, 2048, 0);
  k_gemm_qkv<<<dim3(32, 24), 256, 0, stream>>>(xb, wqkv, cosT, sinT, Qb, Kb, Vt);
  k_attn<<<dim3(16, 64), 256, 0, stream>>>(Qb, Kb, Vt, ctxb);
  k_gemm_out<<<dim3(32, 16), 256, 0, stream>>>(ctxb, wo_t, out);
}

// Round 3
// 294.328 us; speedup vs baseline: 1.6380x; 1.5780x over previous
//
#include <hip/hip_runtime.h>
#include <hip/hip_bf16.h>

using bf16 = __bf16;
using bf16x8 = __attribute__((ext_vector_type(8))) __bf16;
using bf16x4 = __attribute__((ext_vector_type(4))) __bf16;
using f32x4  = __attribute__((ext_vector_type(4))) float;

typedef const void __attribute__((address_space(1)))* gas_p;
typedef void __attribute__((address_space(3)))* las_p;

#define GLD16(g, l) __builtin_amdgcn_global_load_lds((gas_p)(const void*)(g), (las_p)(void*)(l), 16, 0, 0)

__device__ __forceinline__ bf16x8 lds_ld8(const void* p) {
  union { uint4 u; bf16x8 v; } c;
  c.u = *(const uint4*)p;
  return c.v;
}
__device__ __forceinline__ bf16x8 g_ld8(const bf16* p) {
  union { uint4 u; bf16x8 v; } c;
  c.u = *(const uint4*)p;
  return c.v;
}

// pack 4 f32 -> 4 bf16 in a uint2 (memory order p0,p1,p2,p3)
__device__ __forceinline__ uint2 pack4(float p0, float p1, float p2, float p3) {
  union { bf16 h[4]; uint2 u; } c;
  c.h[0] = (bf16)p0; c.h[1] = (bf16)p1; c.h[2] = (bf16)p2; c.h[3] = (bf16)p3;
  return c.u;
}

// ---------------- f32 -> bf16 elementwise convert ----------------
__global__ void k_convert(const float* __restrict__ in, bf16* __restrict__ out, int n4) {
  int i = blockIdx.x * blockDim.x + threadIdx.x;
  if (i >= n4) return;
  float4 f = ((const float4*)in)[i];
  bf16x4 o;
  o[0] = (bf16)f.x; o[1] = (bf16)f.y; o[2] = (bf16)f.z; o[3] = (bf16)f.w;
  ((bf16x4*)out)[i] = o;
}

// ---------------- transpose + convert weights: W[K=2048][N] -> Wt[N][2048] bf16 ----------------
__global__ void k_transp(const float* __restrict__ W, bf16* __restrict__ Wt, int N, int rowOff) {
  __shared__ float tile[64][65];
  const int n0 = blockIdx.x * 64, k0 = blockIdx.y * 64;
  const int t = threadIdx.x;
#pragma unroll
  for (int i = 0; i < 16; ++i) {
    int idx = t + i * 256; int r = idx >> 6, c = idx & 63;
    tile[r][c] = W[(size_t)(k0 + r) * N + n0 + c];
  }
  __syncthreads();
#pragma unroll
  for (int i = 0; i < 16; ++i) {
    int idx = t + i * 256; int r = idx >> 6, c = idx & 63;
    Wt[(size_t)(rowOff + n0 + r) * 2048 + k0 + c] = (bf16)tile[c][r];
  }
}

// ---------------- GEMM main loop: C[128x128] += A[128xK] * Bt[128xK]^T, K=2048, BK=32 ----------------
__device__ __forceinline__ void gemm_main(const bf16* __restrict__ A, const bf16* __restrict__ Bt,
                                          int brow, int bcol, int tid, f32x4 (&acc)[4][4],
                                          char* ldsA, char* ldsB) {
  const int lane = tid & 63;
  const int l15 = lane & 15, l4 = lane >> 4;
  const int wid = tid >> 6, wr = wid >> 1, wc = wid & 1;
  const int srow = tid >> 2;
  const int sseg = (tid & 3) ^ (srow & 3);   // pre-swizzled global source (m173 pattern)
  const bf16* ga = A  + (size_t)(brow + srow) * 2048 + sseg * 8;
  const bf16* gb = Bt + (size_t)(bcol + srow) * 2048 + sseg * 8;
  char* la = ldsA + tid * 16;
  char* lb = ldsB + tid * 16;
  const int roff = (l15 & 3) << 4;

  for (int k0 = 0; k0 < 2048; k0 += 32) {
    __syncthreads();
    GLD16(ga + k0, la);
    GLD16(ga + k0 + (size_t)64 * 2048, la + 4096);
    GLD16(gb + k0, lb);
    GLD16(gb + k0 + (size_t)64 * 2048, lb + 4096);
    __syncthreads();
    bf16x8 af[4], bfr[4];
#pragma unroll
    for (int m = 0; m < 4; ++m)
      af[m] = lds_ld8(ldsA + (wr * 64 + m * 16 + l15) * 64 + ((l4 << 4) ^ roff));
#pragma unroll
    for (int n = 0; n < 4; ++n)
      bfr[n] = lds_ld8(ldsB + (wc * 64 + n * 16 + l15) * 64 + ((l4 << 4) ^ roff));
#pragma unroll
    for (int m = 0; m < 4; ++m)
#pragma unroll
      for (int n = 0; n < 4; ++n)
        acc[m][n] = __builtin_amdgcn_mfma_f32_16x16x32_bf16(af[m], bfr[n], acc[m][n], 0, 0, 0);
  }
}

// ---------------- QKV GEMM + RoPE epilogue (V written transposed) ----------------
__global__ __launch_bounds__(256) void k_gemm_qkv(const bf16* __restrict__ A, const bf16* __restrict__ Bt,
    const float* __restrict__ cosT, const float* __restrict__ sinT,
    bf16* __restrict__ Qb, bf16* __restrict__ Kb, bf16* __restrict__ Vt) {
  __shared__ __align__(16) char ldsA[8192];
  __shared__ __align__(16) char ldsB[8192];
  const int tid = threadIdx.x;
  const int brow = blockIdx.x * 128, bcol = blockIdx.y * 128;
  f32x4 zero = {0.f, 0.f, 0.f, 0.f};
  f32x4 acc[4][4];
#pragma unroll
  for (int m = 0; m < 4; ++m)
#pragma unroll
    for (int n = 0; n < 4; ++n) acc[m][n] = zero;

  gemm_main(A, Bt, brow, bcol, tid, acc, ldsA, ldsB);

  const int lane = tid & 63, l15 = lane & 15, l4 = lane >> 4;
  const int wid = tid >> 6, wr = wid >> 1, wc = wid & 1;
  const int base64 = bcol + wc * 64;       // wave-uniform; one head per wave block
  const int rbase  = brow + wr * 64;

  if (base64 < 2048) {                      // Q segment (RoPE + 1/sqrt(64) scale)
    const int h = base64 >> 6;
#pragma unroll
    for (int m = 0; m < 4; ++m)
#pragma unroll
      for (int r = 0; r < 4; ++r) {
        const int row = rbase + m * 16 + l4 * 4 + r;
        const int b = row >> 11, s = row & 2047;
        float o[4];
#pragma unroll
        for (int n = 0; n < 4; ++n) {
          const int d = n * 16 + l15;
          const float cv = cosT[s * 64 + d], sv = sinT[s * 64 + d];
          const float t = acc[m][n][r], p = acc[m][n ^ 2][r];
          o[n] = (t * cv + ((n < 2) ? -p : p) * sv) * 0.125f;
        }
        bf16* dst = Qb + ((size_t)((b * 32 + h) * 2048 + s)) * 64;
#pragma unroll
        for (int n = 0; n < 4; ++n) dst[n * 16 + l15] = (bf16)o[n];
      }
  } else if (base64 < 2560) {               // K segment (RoPE)
    const int h = (base64 - 2048) >> 6;
#pragma unroll
    for (int m = 0; m < 4; ++m)
#pragma unroll
      for (int r = 0; r < 4; ++r) {
        const int row = rbase + m * 16 + l4 * 4 + r;
        const int b = row >> 11, s = row & 2047;
        float o[4];
#pragma unroll
        for (int n = 0; n < 4; ++n) {
          const int d = n * 16 + l15;
          const float cv = cosT[s * 64 + d], sv = sinT[s * 64 + d];
          const float t = acc[m][n][r], p = acc[m][n ^ 2][r];
          o[n] = t * cv + ((n < 2) ? -p : p) * sv;
        }
        bf16* dst = Kb + ((size_t)((b * 8 + h) * 2048 + s)) * 64;
#pragma unroll
        for (int n = 0; n < 4; ++n) dst[n * 16 + l15] = (bf16)o[n];
      }
  } else {                                  // V segment -> transposed Vt[b][hk][d][s]
    const int h = (base64 - 2560) >> 6;
#pragma unroll
    for (int m = 0; m < 4; ++m)
#pragma unroll
      for (int r = 0; r < 4; ++r) {
        const int row = rbase + m * 16 + l4 * 4 + r;
        const int b = row >> 11, s = row & 2047;
#pragma unroll
        for (int n = 0; n < 4; ++n) {
          const int d = n * 16 + l15;
          Vt[((size_t)((b * 8 + h) * 64 + d)) * 2048 + s] = (bf16)acc[m][n][r];
        }
      }
  }
}

// ---------------- Flash attention (causal, GQA), swapped-operand softmax ----------------
// sc = mfma(K,Q): lane (q=l15) holds a full kv-slice of one q-row -> in-lane softmax,
// only 2 shfl_xor per reduce. PV computed as O^T = V^T * P so rescale/normalize stay
// lane-local. P roundtrip: 4x ds_write_b64 + 2x ds_read_b128 per mi, XOR-swizzled.
__global__ __launch_bounds__(256) void k_attn(const bf16* __restrict__ Qb, const bf16* __restrict__ Kb,
                                              const bf16* __restrict__ Vt, bf16* __restrict__ ctx) {
  __shared__ __align__(16) char pl[4 * 2 * 2048];   // per-wave per-mi P [16 q][64 kv]
  const int tid = threadIdx.x, lane = tid & 63, w = tid >> 6;
  const int l15 = lane & 15, l4 = lane >> 4;
  const int x = blockIdx.x;
  int c;                                     // 32-row q-chunk; per-block total ~const
  switch (w) { case 0: c = 63 - x; break; case 1: c = x; break;
               case 2: c = 32 + x; break; default: c = 31 - x; }
  const int q0 = c * 32;
  const int bh = blockIdx.y, b = bh >> 5, h = bh & 31, hk = h >> 2;
  const int sw = (l15 & 7) << 4;
  char* plw = pl + w * 4096;

  const bf16* qg = Qb + ((size_t)((b * 32 + h) * 2048) + q0) * 64;
  const bf16* kg = Kb + ((size_t)((b * 8 + hk) * 2048)) * 64;
  const bf16* vg = Vt + ((size_t)((b * 8 + hk) * 64)) * 2048;

  // Q as B-fragments: col=l15 -> q row, k = d = kk*32 + l4*8 + j
  bf16x8 bq[2][2];
#pragma unroll
  for (int mi = 0; mi < 2; ++mi)
#pragma unroll
    for (int kk = 0; kk < 2; ++kk)
      bq[mi][kk] = g_ld8(qg + (mi * 16 + l15) * 64 + kk * 32 + l4 * 8);

  f32x4 zero = {0.f, 0.f, 0.f, 0.f};
  f32x4 o[2][4];    // O^T: col=l15=q, row -> d = n*16 + l4*4 + r
#pragma unroll
  for (int mi = 0; mi < 2; ++mi)
#pragma unroll
    for (int n = 0; n < 4; ++n) o[mi][n] = zero;
  float mrow[2] = {-3.0e38f, -3.0e38f};
  float lrow[2] = {0.f, 0.f};

  const int nfull = q0 >> 6;
  for (int kt = 0; kt <= nfull; ++kt) {
    const int kv0 = kt * 64;
    // ---- K fragments (A: row=l15 -> kv, k = d) ----
    bf16x8 ak[4][2];
#pragma unroll
    for (int n = 0; n < 4; ++n)
#pragma unroll
      for (int kk = 0; kk < 2; ++kk)
        ak[n][kk] = g_ld8(kg + (size_t)(kv0 + n * 16 + l15) * 64 + kk * 32 + l4 * 8);
    // ---- V^T fragments, issued early (A: row=l15 -> d, k = kv) ----
    bf16x8 av[4][2];
#pragma unroll
    for (int n = 0; n < 4; ++n)
#pragma unroll
      for (int kk = 0; kk < 2; ++kk)
        av[n][kk] = g_ld8(vg + (size_t)(n * 16 + l15) * 2048 + kv0 + kk * 32 + l4 * 8);

    // ---- scores: sc[mi][n], lane holds q=l15, kv = kv0 + n*16 + l4*4 + r ----
    f32x4 sc[2][4];
#pragma unroll
    for (int mi = 0; mi < 2; ++mi)
#pragma unroll
      for (int n = 0; n < 4; ++n) {
        sc[mi][n] = __builtin_amdgcn_mfma_f32_16x16x32_bf16(ak[n][0], bq[mi][0], zero, 0, 0, 0);
        sc[mi][n] = __builtin_amdgcn_mfma_f32_16x16x32_bf16(ak[n][1], bq[mi][1], sc[mi][n], 0, 0, 0);
      }
    if (kt == nfull) {   // diagonal: mask kv > q
#pragma unroll
      for (int mi = 0; mi < 2; ++mi) {
        const int q = q0 + mi * 16 + l15;
#pragma unroll
        for (int n = 0; n < 4; ++n)
#pragma unroll
          for (int r = 0; r < 4; ++r)
            if (kv0 + n * 16 + l4 * 4 + r > q) sc[mi][n][r] = -3.0e30f;
      }
    }

#pragma unroll
    for (int mi = 0; mi < 2; ++mi) {
      // in-lane max tree (16 vals) + 2 cross shfls
      float t0 = fmaxf(fmaxf(sc[mi][0][0], sc[mi][0][1]), fmaxf(sc[mi][0][2], sc[mi][0][3]));
      float t1 = fmaxf(fmaxf(sc[mi][1][0], sc[mi][1][1]), fmaxf(sc[mi][1][2], sc[mi][1][3]));
      float t2 = fmaxf(fmaxf(sc[mi][2][0], sc[mi][2][1]), fmaxf(sc[mi][2][2], sc[mi][2][3]));
      float t3 = fmaxf(fmaxf(sc[mi][3][0], sc[mi][3][1]), fmaxf(sc[mi][3][2], sc[mi][3][3]));
      float mx = fmaxf(fmaxf(t0, t1), fmaxf(t2, t3));
      mx = fmaxf(mx, __shfl_xor(mx, 16));
      mx = fmaxf(mx, __shfl_xor(mx, 32));
      // defer-max (T13): rescale only if max grew by > 8
      if (!__all(mx <= mrow[mi] + 8.f)) {
        const float mn = fmaxf(mrow[mi], mx);
        const float corr = __expf(mrow[mi] - mn);
        mrow[mi] = mn;
        lrow[mi] *= corr;
#pragma unroll
        for (int n = 0; n < 4; ++n) o[mi][n] *= corr;
      }
      const float m = mrow[mi];
      float p[4][4];
#pragma unroll
      for (int n = 0; n < 4; ++n)
#pragma unroll
        for (int r = 0; r < 4; ++r) p[n][r] = __expf(sc[mi][n][r] - m);
      float s0 = (p[0][0] + p[0][1]) + (p[0][2] + p[0][3]);
      float s1 = (p[1][0] + p[1][1]) + (p[1][2] + p[1][3]);
      float s2 = (p[2][0] + p[2][1]) + (p[2][2] + p[2][3]);
      float s3 = (p[3][0] + p[3][1]) + (p[3][2] + p[3][3]);
      float rs = (s0 + s1) + (s2 + s3);
      rs += __shfl_xor(rs, 16);
      rs += __shfl_xor(rs, 32);
      lrow[mi] += rs;
      // P -> LDS, packed b64 writes (kv-contiguous per lane)
      char* base = plw + mi * 2048;
#pragma unroll
      for (int n = 0; n < 4; ++n)
        *(uint2*)(base + l15 * 128 + ((n * 32 + l4 * 8) ^ sw)) =
            pack4(p[n][0], p[n][1], p[n][2], p[n][3]);
    }

    // ---- PV: O^T = V^T * P ----
    bf16x8 pb[2][2];
#pragma unroll
    for (int mi = 0; mi < 2; ++mi)
#pragma unroll
      for (int kk = 0; kk < 2; ++kk)
        pb[mi][kk] = lds_ld8(plw + mi * 2048 + l15 * 128 + ((kk * 64 + l4 * 16) ^ sw));
#pragma unroll
    for (int mi = 0; mi < 2; ++mi)
#pragma unroll
      for (int n = 0; n < 4; ++n) {
        o[mi][n] = __builtin_amdgcn_mfma_f32_16x16x32_bf16(av[n][0], pb[mi][0], o[mi][n], 0, 0, 0);
        o[mi][n] = __builtin_amdgcn_mfma_f32_16x16x32_bf16(av[n][1], pb[mi][1], o[mi][n], 0, 0, 0);
      }
  }

  // ---- normalize (lane-local) + transpose via LDS + coalesced store ----
#pragma unroll
  for (int mi = 0; mi < 2; ++mi) {
    const float inv = 1.0f / lrow[mi];
    char* base = plw + mi * 2048;
#pragma unroll
    for (int n = 0; n < 4; ++n)
      *(uint2*)(base + l15 * 128 + ((n * 32 + l4 * 8) ^ sw)) =
          pack4(o[mi][n][0] * inv, o[mi][n][1] * inv, o[mi][n][2] * inv, o[mi][n][3] * inv);
#pragma unroll
    for (int kk = 0; kk < 2; ++kk) {
      uint4 val = *(const uint4*)(base + l15 * 128 + ((kk * 64 + l4 * 16) ^ sw));
      *(uint4*)(ctx + ((size_t)(b * 2048 + q0 + mi * 16 + l15)) * 2048 + h * 64 + kk * 32 + l4 * 8) = val;
    }
  }
}

// ---------------- Output GEMM: ctx @ Wo -> f32 ----------------
__global__ __launch_bounds__(256) void k_gemm_out(const bf16* __restrict__ A, const bf16* __restrict__ Bt,
                                                  float* __restrict__ out) {
  __shared__ __align__(16) char ldsA[8192];
  __shared__ __align__(16) char ldsB[8192];
  const int tid = threadIdx.x;
  const int brow = blockIdx.x * 128, bcol = blockIdx.y * 128;
  f32x4 zero = {0.f, 0.f, 0.f, 0.f};
  f32x4 acc[4][4];
#pragma unroll
  for (int m = 0; m < 4; ++m)
#pragma unroll
    for (int n = 0; n < 4; ++n) acc[m][n] = zero;

  gemm_main(A, Bt, brow, bcol, tid, acc, ldsA, ldsB);

  const int lane = tid & 63, l15 = lane & 15, l4 = lane >> 4;
  const int wid = tid >> 6, wr = wid >> 1, wc = wid & 1;
#pragma unroll
  for (int m = 0; m < 4; ++m)
#pragma unroll
    for (int r = 0; r < 4; ++r) {
      const int row = brow + wr * 64 + m * 16 + l4 * 4 + r;
      float* dst = out + (size_t)row * 2048 + bcol + wc * 64;
#pragma unroll
      for (int n = 0; n < 4; ++n) dst[n * 16 + l15] = acc[m][n][r];
    }
}

extern "C" void kernel_launch(void* const* d_in, const int* in_sizes, int n_in,
                              void* d_out, int out_size, void* d_ws, size_t ws_size,
                              hipStream_t stream) {
  (void)in_sizes; (void)n_in; (void)out_size;
  if (ws_size < (size_t)79691776) return;   // need ~76 MB scratch
  const float* x    = (const float*)d_in[0];
  // d_in[1] = mask (causal, hardcoded)
  const float* cosT = (const float*)d_in[2];
  const float* sinT = (const float*)d_in[3];
  const float* Wq   = (const float*)d_in[4];
  const float* Wk   = (const float*)d_in[5];
  const float* Wv   = (const float*)d_in[6];
  const float* Wo   = (const float*)d_in[7];
  char* ws = (char*)d_ws;
  bf16* xb   = (bf16*)(ws + 0);            // [4096][2048]
  bf16* wqkv = (bf16*)(ws + 16777216);     // [3072][2048]  (Wq^T | Wk^T | Wv^T)
  bf16* wo_t = (bf16*)(ws + 29360128);     // [2048][2048]
  bf16* Qb   = (bf16*)(ws + 37748736);     // [2][32][2048][64]
  bf16* Kb   = (bf16*)(ws + 54525952);     // [2][8][2048][64]
  bf16* Vt   = (bf16*)(ws + 58720256);     // [2][8][64][2048]  (transposed V)
  bf16* ctxb = (bf16*)(ws + 62914560);     // [4096][2048]
  float* out = (float*)d_out;

  k_convert<<<8192, 256, 0, stream>>>(x, xb, 2097152);
  k_transp<<<dim3(32, 32), 256, 0, stream>>>(Wq, wqkv, 2048, 0);
  k_transp<<<dim3(8, 32),  256, 0, stream>>>(Wk, wqkv, 512, 2048);
  k_transp<<<dim3(8, 32),  256, 0, stream>>>(Wv, wqkv, 512, 2560);
  k_transp<<<dim3(32, 32), 256, 0, stream>>>(Wo, wo_t, 2048, 0);
  k_gemm_qkv<<<dim3(32, 24), 256, 0, stream>>>(xb, wqkv, cosT, sinT, Qb, Kb, Vt);
  k_attn<<<dim3(16, 64), 256, 0, stream>>>(Qb, Kb, Vt, ctxb);
  k_gemm_out<<<dim3(32, 16), 256, 0, stream>>>(ctxb, wo_t, out);
}

// Round 4
// 272.205 us; speedup vs baseline: 1.7712x; 1.0813x over previous
//
#include <hip/hip_runtime.h>
#include <hip/hip_bf16.h>

using bf16 = __bf16;
using bf16x8 = __attribute__((ext_vector_type(8))) __bf16;
using bf16x4 = __attribute__((ext_vector_type(4))) __bf16;
using f32x4  = __attribute__((ext_vector_type(4))) float;

typedef const void __attribute__((address_space(1)))* gas_p;
typedef void __attribute__((address_space(3)))* las_p;

#define GLD16(g, l) __builtin_amdgcn_global_load_lds((gas_p)(const void*)(g), (las_p)(void*)(l), 16, 0, 0)

__device__ __forceinline__ bf16x8 lds_ld8(const void* p) {
  union { uint4 u; bf16x8 v; } c;
  c.u = *(const uint4*)p;
  return c.v;
}
__device__ __forceinline__ bf16x8 g_ld8(const bf16* p) {
  union { uint4 u; bf16x8 v; } c;
  c.u = *(const uint4*)p;
  return c.v;
}
// single-instruction 2^x
__device__ __forceinline__ float fexp2(float x) {
  float r; asm("v_exp_f32 %0, %1" : "=v"(r) : "v"(x)); return r;
}
// pack 4 f32 -> 4 bf16 in a uint2 (memory order p0,p1,p2,p3)
__device__ __forceinline__ uint2 pack4(float p0, float p1, float p2, float p3) {
  union { bf16 h[4]; uint2 u; } c;
  c.h[0] = (bf16)p0; c.h[1] = (bf16)p1; c.h[2] = (bf16)p2; c.h[3] = (bf16)p3;
  return c.u;
}

// ---------------- f32 -> bf16 elementwise convert ----------------
__global__ void k_convert(const float* __restrict__ in, bf16* __restrict__ out, int n4) {
  int i = blockIdx.x * blockDim.x + threadIdx.x;
  if (i >= n4) return;
  float4 f = ((const float4*)in)[i];
  bf16x4 o;
  o[0] = (bf16)f.x; o[1] = (bf16)f.y; o[2] = (bf16)f.z; o[3] = (bf16)f.w;
  ((bf16x4*)out)[i] = o;
}

// ---------------- transpose + convert weights: W[K=2048][N] -> Wt[N][2048] bf16 ----------------
__global__ void k_transp(const float* __restrict__ W, bf16* __restrict__ Wt, int N, int rowOff) {
  __shared__ float tile[64][65];
  const int n0 = blockIdx.x * 64, k0 = blockIdx.y * 64;
  const int t = threadIdx.x;
#pragma unroll
  for (int i = 0; i < 16; ++i) {
    int idx = t + i * 256; int r = idx >> 6, c = idx & 63;
    tile[r][c] = W[(size_t)(k0 + r) * N + n0 + c];
  }
  __syncthreads();
#pragma unroll
  for (int i = 0; i < 16; ++i) {
    int idx = t + i * 256; int r = idx >> 6, c = idx & 63;
    Wt[(size_t)(rowOff + n0 + r) * 2048 + k0 + c] = (bf16)tile[c][r];
  }
}

// ---------------- GEMM main loop: C[128x128] += A[128xK] * Bt[128xK]^T, K=2048, BK=32 ----------------
__device__ __forceinline__ void gemm_main(const bf16* __restrict__ A, const bf16* __restrict__ Bt,
                                          int brow, int bcol, int tid, f32x4 (&acc)[4][4],
                                          char* ldsA, char* ldsB) {
  const int lane = tid & 63;
  const int l15 = lane & 15, l4 = lane >> 4;
  const int wid = tid >> 6, wr = wid >> 1, wc = wid & 1;
  const int srow = tid >> 2;
  const int sseg = (tid & 3) ^ (srow & 3);   // pre-swizzled global source (m173 pattern)
  const bf16* ga = A  + (size_t)(brow + srow) * 2048 + sseg * 8;
  const bf16* gb = Bt + (size_t)(bcol + srow) * 2048 + sseg * 8;
  char* la = ldsA + tid * 16;
  char* lb = ldsB + tid * 16;
  const int roff = (l15 & 3) << 4;

  for (int k0 = 0; k0 < 2048; k0 += 32) {
    __syncthreads();
    GLD16(ga + k0, la);
    GLD16(ga + k0 + (size_t)64 * 2048, la + 4096);
    GLD16(gb + k0, lb);
    GLD16(gb + k0 + (size_t)64 * 2048, lb + 4096);
    __syncthreads();
    bf16x8 af[4], bfr[4];
#pragma unroll
    for (int m = 0; m < 4; ++m)
      af[m] = lds_ld8(ldsA + (wr * 64 + m * 16 + l15) * 64 + ((l4 << 4) ^ roff));
#pragma unroll
    for (int n = 0; n < 4; ++n)
      bfr[n] = lds_ld8(ldsB + (wc * 64 + n * 16 + l15) * 64 + ((l4 << 4) ^ roff));
#pragma unroll
    for (int m = 0; m < 4; ++m)
#pragma unroll
      for (int n = 0; n < 4; ++n)
        acc[m][n] = __builtin_amdgcn_mfma_f32_16x16x32_bf16(af[m], bfr[n], acc[m][n], 0, 0, 0);
  }
}

// ---------------- QKV GEMM + RoPE epilogue (V written transposed) ----------------
// Q scale folds 1/sqrt(64) * log2(e) so attention softmax can use exp2 directly.
__global__ __launch_bounds__(256) void k_gemm_qkv(const bf16* __restrict__ A, const bf16* __restrict__ Bt,
    const float* __restrict__ cosT, const float* __restrict__ sinT,
    bf16* __restrict__ Qb, bf16* __restrict__ Kb, bf16* __restrict__ Vt) {
  __shared__ __align__(16) char ldsA[8192];
  __shared__ __align__(16) char ldsB[8192];
  const int tid = threadIdx.x;
  const int brow = blockIdx.x * 128, bcol = blockIdx.y * 128;
  f32x4 zero = {0.f, 0.f, 0.f, 0.f};
  f32x4 acc[4][4];
#pragma unroll
  for (int m = 0; m < 4; ++m)
#pragma unroll
    for (int n = 0; n < 4; ++n) acc[m][n] = zero;

  gemm_main(A, Bt, brow, bcol, tid, acc, ldsA, ldsB);

  const int lane = tid & 63, l15 = lane & 15, l4 = lane >> 4;
  const int wid = tid >> 6, wr = wid >> 1, wc = wid & 1;
  const int base64 = bcol + wc * 64;       // wave-uniform; one head per wave block
  const int rbase  = brow + wr * 64;

  if (base64 < 2048) {                      // Q segment (RoPE + 0.125*log2e scale)
    const int h = base64 >> 6;
#pragma unroll
    for (int m = 0; m < 4; ++m)
#pragma unroll
      for (int r = 0; r < 4; ++r) {
        const int row = rbase + m * 16 + l4 * 4 + r;
        const int b = row >> 11, s = row & 2047;
        float o[4];
#pragma unroll
        for (int n = 0; n < 4; ++n) {
          const int d = n * 16 + l15;
          const float cv = cosT[s * 64 + d], sv = sinT[s * 64 + d];
          const float t = acc[m][n][r], p = acc[m][n ^ 2][r];
          o[n] = (t * cv + ((n < 2) ? -p : p) * sv) * 0.18033688f;
        }
        bf16* dst = Qb + ((size_t)((b * 32 + h) * 2048 + s)) * 64;
#pragma unroll
        for (int n = 0; n < 4; ++n) dst[n * 16 + l15] = (bf16)o[n];
      }
  } else if (base64 < 2560) {               // K segment (RoPE)
    const int h = (base64 - 2048) >> 6;
#pragma unroll
    for (int m = 0; m < 4; ++m)
#pragma unroll
      for (int r = 0; r < 4; ++r) {
        const int row = rbase + m * 16 + l4 * 4 + r;
        const int b = row >> 11, s = row & 2047;
        float o[4];
#pragma unroll
        for (int n = 0; n < 4; ++n) {
          const int d = n * 16 + l15;
          const float cv = cosT[s * 64 + d], sv = sinT[s * 64 + d];
          const float t = acc[m][n][r], p = acc[m][n ^ 2][r];
          o[n] = t * cv + ((n < 2) ? -p : p) * sv;
        }
        bf16* dst = Kb + ((size_t)((b * 8 + h) * 2048 + s)) * 64;
#pragma unroll
        for (int n = 0; n < 4; ++n) dst[n * 16 + l15] = (bf16)o[n];
      }
  } else {                                  // V segment -> transposed Vt[b][hk][d][s]
    const int h = (base64 - 2560) >> 6;
#pragma unroll
    for (int m = 0; m < 4; ++m)
#pragma unroll
      for (int r = 0; r < 4; ++r) {
        const int row = rbase + m * 16 + l4 * 4 + r;
        const int b = row >> 11, s = row & 2047;
#pragma unroll
        for (int n = 0; n < 4; ++n) {
          const int d = n * 16 + l15;
          Vt[((size_t)((b * 8 + h) * 64 + d)) * 2048 + s] = (bf16)acc[m][n][r];
        }
      }
  }
}

// ---------------- Flash attention (causal, GQA) ----------------
// Balanced dual-chunk waves: each wave owns chunks (u, 63-u) and shares one K/V
// fragment load per kv-tile between them -> every wave does ~34 chunk-tiles.
// Swapped-operand softmax (lane-local rows), exp2 via folded log2e, T5 setprio.
struct CState {
  bf16x8 bq[2][2];
  f32x4  o[2][4];
  float  m[2], l[2];
};

__device__ __forceinline__ void attn_tile(CState& st, const bf16x8 (&ak)[4][2], const bf16x8 (&av)[4][2],
                                          char* plc, int l15, int l4, int sw,
                                          int q0, int kv0, bool masked) {
  const f32x4 zero = {0.f, 0.f, 0.f, 0.f};
#pragma unroll
  for (int mi = 0; mi < 2; ++mi) {
    f32x4 sc[4];
    __builtin_amdgcn_s_setprio(1);
#pragma unroll
    for (int n = 0; n < 4; ++n) {
      sc[n] = __builtin_amdgcn_mfma_f32_16x16x32_bf16(ak[n][0], st.bq[mi][0], zero, 0, 0, 0);
      sc[n] = __builtin_amdgcn_mfma_f32_16x16x32_bf16(ak[n][1], st.bq[mi][1], sc[n], 0, 0, 0);
    }
    __builtin_amdgcn_s_setprio(0);
    if (masked) {
      const int q = q0 + mi * 16 + l15;
#pragma unroll
      for (int n = 0; n < 4; ++n)
#pragma unroll
        for (int r = 0; r < 4; ++r)
          if (kv0 + n * 16 + l4 * 4 + r > q) sc[n][r] = -3.0e30f;
    }
    float t0 = fmaxf(fmaxf(sc[0][0], sc[0][1]), fmaxf(sc[0][2], sc[0][3]));
    float t1 = fmaxf(fmaxf(sc[1][0], sc[1][1]), fmaxf(sc[1][2], sc[1][3]));
    float t2 = fmaxf(fmaxf(sc[2][0], sc[2][1]), fmaxf(sc[2][2], sc[2][3]));
    float t3 = fmaxf(fmaxf(sc[3][0], sc[3][1]), fmaxf(sc[3][2], sc[3][3]));
    float mx = fmaxf(fmaxf(t0, t1), fmaxf(t2, t3));
    mx = fmaxf(mx, __shfl_xor(mx, 16));
    mx = fmaxf(mx, __shfl_xor(mx, 32));
    // defer-max (T13): rescale only if max grew by > 11.5 (log2 units)
    if (!__all(mx <= st.m[mi] + 11.5f)) {
      const float mn = fmaxf(st.m[mi], mx);
      const float corr = fexp2(st.m[mi] - mn);
      st.m[mi] = mn;
      st.l[mi] *= corr;
#pragma unroll
      for (int n = 0; n < 4; ++n) st.o[mi][n] *= corr;
    }
    const float m = st.m[mi];
    float p[4][4];
#pragma unroll
    for (int n = 0; n < 4; ++n)
#pragma unroll
      for (int r = 0; r < 4; ++r) p[n][r] = fexp2(sc[n][r] - m);
    float s0 = (p[0][0] + p[0][1]) + (p[0][2] + p[0][3]);
    float s1 = (p[1][0] + p[1][1]) + (p[1][2] + p[1][3]);
    float s2 = (p[2][0] + p[2][1]) + (p[2][2] + p[2][3]);
    float s3 = (p[3][0] + p[3][1]) + (p[3][2] + p[3][3]);
    float rs = (s0 + s1) + (s2 + s3);
    rs += __shfl_xor(rs, 16);
    rs += __shfl_xor(rs, 32);
    st.l[mi] += rs;
    char* base = plc + mi * 2048;
#pragma unroll
    for (int n = 0; n < 4; ++n)
      *(uint2*)(base + l15 * 128 + ((n * 32 + l4 * 8) ^ sw)) =
          pack4(p[n][0], p[n][1], p[n][2], p[n][3]);
  }
  // PV: O^T += V^T * P
  bf16x8 pb[2][2];
#pragma unroll
  for (int mi = 0; mi < 2; ++mi)
#pragma unroll
    for (int kk = 0; kk < 2; ++kk)
      pb[mi][kk] = lds_ld8(plc + mi * 2048 + l15 * 128 + ((kk * 64 + l4 * 16) ^ sw));
  __builtin_amdgcn_s_setprio(1);
#pragma unroll
  for (int mi = 0; mi < 2; ++mi)
#pragma unroll
    for (int n = 0; n < 4; ++n) {
      st.o[mi][n] = __builtin_amdgcn_mfma_f32_16x16x32_bf16(av[n][0], pb[mi][0], st.o[mi][n], 0, 0, 0);
      st.o[mi][n] = __builtin_amdgcn_mfma_f32_16x16x32_bf16(av[n][1], pb[mi][1], st.o[mi][n], 0, 0, 0);
    }
  __builtin_amdgcn_s_setprio(0);
}

__device__ __forceinline__ void attn_epi(CState& st, char* plc, int l15, int l4, int sw,
                                         bf16* __restrict__ ctx, int b, int h, int q0) {
#pragma unroll
  for (int mi = 0; mi < 2; ++mi) {
    const float inv = 1.0f / st.l[mi];
    char* base = plc + mi * 2048;
#pragma unroll
    for (int n = 0; n < 4; ++n)
      *(uint2*)(base + l15 * 128 + ((n * 32 + l4 * 8) ^ sw)) =
          pack4(st.o[mi][n][0] * inv, st.o[mi][n][1] * inv, st.o[mi][n][2] * inv, st.o[mi][n][3] * inv);
#pragma unroll
    for (int kk = 0; kk < 2; ++kk) {
      uint4 val = *(const uint4*)(base + l15 * 128 + ((kk * 64 + l4 * 16) ^ sw));
      *(uint4*)(ctx + ((size_t)(b * 2048 + q0 + mi * 16 + l15)) * 2048 + h * 64 + kk * 32 + l4 * 8) = val;
    }
  }
}

__global__ __launch_bounds__(256) void k_attn(const bf16* __restrict__ Qb, const bf16* __restrict__ Kb,
                                              const bf16* __restrict__ Vt, bf16* __restrict__ ctx) {
  __shared__ __align__(16) char pl[4 * 8192];   // per-wave: 2 chunks x 2 mi x 2KB
  const int tid = threadIdx.x, lane = tid & 63, w = tid >> 6;
  const int l15 = lane & 15, l4 = lane >> 4;
  // XCD-aware bijective remap (T1): each XCD gets 8 contiguous bh values
  const int p = (int)blockIdx.x + (int)blockIdx.y * 8;   // physical dispatch id; XCD = p&7
  const int y  = ((p & 7) << 3) | ((p >> 3) & 7);        // logical bh
  const int xl = p >> 6;                                  // logical x in [0,8)
  const int u = xl * 4 + w;                               // wave-unit in [0,32)
  const int cA = 63 - u, cB = u;                          // paired chunks: equal total work
  const int q0A = cA * 32, q0B = cB * 32;
  const int nfA = cA >> 1, nfB = cB >> 1;
  const int b = y >> 5, h = y & 31, hk = h >> 2;
  const int sw = (l15 & 7) << 4;
  char* plw = pl + w * 8192;

  const bf16* kg = Kb + ((size_t)((b * 8 + hk) * 2048)) * 64;
  const bf16* vg = Vt + ((size_t)((b * 8 + hk) * 64)) * 2048;
  const bf16* qgA = Qb + ((size_t)((b * 32 + h) * 2048) + q0A) * 64;
  const bf16* qgB = Qb + ((size_t)((b * 32 + h) * 2048) + q0B) * 64;

  const f32x4 zero = {0.f, 0.f, 0.f, 0.f};
  CState A, B;
#pragma unroll
  for (int mi = 0; mi < 2; ++mi) {
#pragma unroll
    for (int kk = 0; kk < 2; ++kk) {
      A.bq[mi][kk] = g_ld8(qgA + (mi * 16 + l15) * 64 + kk * 32 + l4 * 8);
      B.bq[mi][kk] = g_ld8(qgB + (mi * 16 + l15) * 64 + kk * 32 + l4 * 8);
    }
#pragma unroll
    for (int n = 0; n < 4; ++n) { A.o[mi][n] = zero; B.o[mi][n] = zero; }
    A.m[mi] = -3.0e38f; B.m[mi] = -3.0e38f;
    A.l[mi] = 0.f;      B.l[mi] = 0.f;
  }

  for (int kt = 0; kt <= nfA; ++kt) {
    const int kv0 = kt * 64;
    bf16x8 ak[4][2], av[4][2];
#pragma unroll
    for (int n = 0; n < 4; ++n)
#pragma unroll
      for (int kk = 0; kk < 2; ++kk) {
        ak[n][kk] = g_ld8(kg + (size_t)(kv0 + n * 16 + l15) * 64 + kk * 32 + l4 * 8);
        av[n][kk] = g_ld8(vg + (size_t)(n * 16 + l15) * 2048 + kv0 + kk * 32 + l4 * 8);
      }
    attn_tile(A, ak, av, plw, l15, l4, sw, q0A, kv0, kt == nfA);
    if (kt <= nfB)
      attn_tile(B, ak, av, plw + 4096, l15, l4, sw, q0B, kv0, kt == nfB);
  }

  attn_epi(A, plw, l15, l4, sw, ctx, b, h, q0A);
  attn_epi(B, plw + 4096, l15, l4, sw, ctx, b, h, q0B);
}

// ---------------- Output GEMM: ctx @ Wo -> f32 ----------------
__global__ __launch_bounds__(256) void k_gemm_out(const bf16* __restrict__ A, const bf16* __restrict__ Bt,
                                                  float* __restrict__ out) {
  __shared__ __align__(16) char ldsA[8192];
  __shared__ __align__(16) char ldsB[8192];
  const int tid = threadIdx.x;
  const int brow = blockIdx.x * 128, bcol = blockIdx.y * 128;
  f32x4 zero = {0.f, 0.f, 0.f, 0.f};
  f32x4 acc[4][4];
#pragma unroll
  for (int m = 0; m < 4; ++m)
#pragma unroll
    for (int n = 0; n < 4; ++n) acc[m][n] = zero;

  gemm_main(A, Bt, brow, bcol, tid, acc, ldsA, ldsB);

  const int lane = tid & 63, l15 = lane & 15, l4 = lane >> 4;
  const int wid = tid >> 6, wr = wid >> 1, wc = wid & 1;
#pragma unroll
  for (int m = 0; m < 4; ++m)
#pragma unroll
    for (int r = 0; r < 4; ++r) {
      const int row = brow + wr * 64 + m * 16 + l4 * 4 + r;
      float* dst = out + (size_t)row * 2048 + bcol + wc * 64;
#pragma unroll
      for (int n = 0; n < 4; ++n) dst[n * 16 + l15] = acc[m][n][r];
    }
}

extern "C" void kernel_launch(void* const* d_in, const int* in_sizes, int n_in,
                              void* d_out, int out_size, void* d_ws, size_t ws_size,
                              hipStream_t stream) {
  (void)in_sizes; (void)n_in; (void)out_size;
  if (ws_size < (size_t)79691776) return;   // need ~76 MB scratch
  const float* x    = (const float*)d_in[0];
  // d_in[1] = mask (causal, hardcoded)
  const float* cosT = (const float*)d_in[2];
  const float* sinT = (const float*)d_in[3];
  const float* Wq   = (const float*)d_in[4];
  const float* Wk   = (const float*)d_in[5];
  const float* Wv   = (const float*)d_in[6];
  const float* Wo   = (const float*)d_in[7];
  char* ws = (char*)d_ws;
  bf16* xb   = (bf16*)(ws + 0);            // [4096][2048]
  bf16* wqkv = (bf16*)(ws + 16777216);     // [3072][2048]  (Wq^T | Wk^T | Wv^T)
  bf16* wo_t = (bf16*)(ws + 29360128);     // [2048][2048]
  bf16* Qb   = (bf16*)(ws + 37748736);     // [2][32][2048][64]
  bf16* Kb   = (bf16*)(ws + 54525952);     // [2][8][2048][64]
  bf16* Vt   = (bf16*)(ws + 58720256);     // [2][8][64][2048]  (transposed V)
  bf16* ctxb = (bf16*)(ws + 62914560);     // [4096][2048]
  float* out = (float*)d_out;

  k_convert<<<8192, 256, 0, stream>>>(x, xb, 2097152);
  k_transp<<<dim3(32, 32), 256, 0, stream>>>(Wq, wqkv, 2048, 0);
  k_transp<<<dim3(8, 32),  256, 0, stream>>>(Wk, wqkv, 512, 2048);
  k_transp<<<dim3(8, 32),  256, 0, stream>>>(Wv, wqkv, 512, 2560);
  k_transp<<<dim3(32, 32), 256, 0, stream>>>(Wo, wo_t, 2048, 0);
  k_gemm_qkv<<<dim3(32, 24), 256, 0, stream>>>(xb, wqkv, cosT, sinT, Qb, Kb, Vt);
  k_attn<<<dim3(8, 64), 256, 0, stream>>>(Qb, Kb, Vt, ctxb);
  k_gemm_out<<<dim3(32, 16), 256, 0, stream>>>(ctxb, wo_t, out);
}